// Round 1
// baseline (276.722 us; speedup 1.0000x reference)
//
#include <hip/hip_runtime.h>

#define BATCH 16
#define C_IN  64
#define HH    64
#define WW    64
#define COUT  64
#define KK    9
#define HW    (HH * WW)     // 4096
#define CK    (C_IN * KK)   // 576

// Transpose weight (Cout, C, 3, 3) -> Wt[ck][o] so the o-run for a fixed
// (c,k) is contiguous and scalar-loadable (s_load_dwordx16).
__global__ void transpose_w_kernel(const float* __restrict__ w,
                                   float* __restrict__ wt) {
    int i = blockIdx.x * 256 + threadIdx.x;  // 0 .. CK*COUT-1 (36864, exact)
    int ck = i >> 6;
    int o  = i & 63;
    wt[i] = w[o * CK + ck];
}

// One wave = 64 consecutive pixels x 32 output channels.
// Block = 256 threads: waves {0,1} -> o-half 0, waves {2,3} -> o-half 1,
// covering 128 consecutive pixels of one image.
__global__ __launch_bounds__(256) void dcn_fwd_kernel(
    const float* __restrict__ x, const float* __restrict__ offset,
    const float* __restrict__ mask, const float* __restrict__ wt,
    const float* __restrict__ bias, float* __restrict__ out) {
    const int t = threadIdx.x;
    // t>>7 is wave-uniform (128-aligned groups); force SGPR so weight reads
    // below become scalar loads.
    const int half  = __builtin_amdgcn_readfirstlane(t >> 7);
    const int obase = half * 32;
    const int pl  = t & 127;
    const int blk = blockIdx.x;
    const int b   = blk >> 5;                  // 32 blocks per image
    const int pix = ((blk & 31) << 7) + pl;    // 0..4095
    const int p = pix >> 6;
    const int q = pix & 63;

    float acc[32];
#pragma unroll
    for (int o = 0; o < 32; ++o) acc[o] = bias[obase + o];

    const float* xb  = x + b * (C_IN * HW);
    const int offb = b * (2 * KK * HW);
    const int mb   = b * (KK * HW);

    for (int k = 0; k < KK; ++k) {
        const int ky = k / 3, kx = k % 3;
        const float oy = offset[offb + (2 * k)     * HW + pix];
        const float ox = offset[offb + (2 * k + 1) * HW + pix];
        const float mk = mask[mb + k * HW + pix];

        const float py = oy + (float)(p - 1 + ky);
        const float px = ox + (float)(q - 1 + kx);
        const float y0f = floorf(py), x0f = floorf(px);
        const float wy = py - y0f, wx = px - x0f;
        const int y0 = (int)y0f, x0 = (int)x0f;
        const int y1 = y0 + 1,   x1 = x0 + 1;

        const float vy0 = (y0 >= 0 && y0 < HH) ? 1.f : 0.f;
        const float vy1 = (y1 >= 0 && y1 < HH) ? 1.f : 0.f;
        const float vx0 = (x0 >= 0 && x0 < WW) ? 1.f : 0.f;
        const float vx1 = (x1 >= 0 && x1 < WW) ? 1.f : 0.f;

        // fold mask + per-corner validity into the bilinear weights
        const float w00 = (1.f - wy) * (1.f - wx) * vy0 * vx0 * mk;
        const float w01 = (1.f - wy) * wx         * vy0 * vx1 * mk;
        const float w10 = wy * (1.f - wx)         * vy1 * vx0 * mk;
        const float w11 = wy * wx                 * vy1 * vx1 * mk;

        const int cy0 = min(max(y0, 0), HH - 1), cy1 = min(max(y1, 0), HH - 1);
        const int cx0 = min(max(x0, 0), WW - 1), cx1 = min(max(x1, 0), WW - 1);
        const int a00 = cy0 * WW + cx0, a01 = cy0 * WW + cx1;
        const int a10 = cy1 * WW + cx0, a11 = cy1 * WW + cx1;

#pragma unroll 2
        for (int c = 0; c < C_IN; ++c) {
            const float* plane = xb + c * HW;
            const float v = w00 * plane[a00] + w01 * plane[a01] +
                            w10 * plane[a10] + w11 * plane[a11];
            // uniform address -> scalar loads (dual-issue with the FMAs)
            const float* wrow = wt + (c * KK + k) * COUT + obase;
#pragma unroll
            for (int o = 0; o < 32; ++o) acc[o] = fmaf(v, wrow[o], acc[o]);
        }
    }

    float* ob = out + b * (COUT * HW) + obase * HW + pix;
#pragma unroll
    for (int o = 0; o < 32; ++o) ob[o * HW] = acc[o];
}

extern "C" void kernel_launch(void* const* d_in, const int* in_sizes, int n_in,
                              void* d_out, int out_size, void* d_ws,
                              size_t ws_size, hipStream_t stream) {
    const float* x    = (const float*)d_in[0];
    const float* off  = (const float*)d_in[1];
    const float* mask = (const float*)d_in[2];
    const float* w    = (const float*)d_in[3];
    const float* bias = (const float*)d_in[4];
    float* out = (float*)d_out;
    float* wt  = (float*)d_ws;  // CK*COUT floats = 147456 B

    transpose_w_kernel<<<(CK * COUT) / 256, 256, 0, stream>>>(w, wt);
    dcn_fwd_kernel<<<(BATCH * HW) / 128, 256, 0, stream>>>(x, off, mask, wt,
                                                           bias, out);
}